// Round 6
// baseline (68.000 us; speedup 1.0000x reference)
//
#include <hip/hip_runtime.h>
#include <hip/hip_fp16.h>

#define NN   2048
#define FIN  128
#define FOUT 64
#define LOG2E 1.44269504088896f

using f16x8 = __attribute__((ext_vector_type(8))) _Float16;
using f16x4 = __attribute__((ext_vector_type(4))) _Float16;
using f16x2 = __attribute__((ext_vector_type(2))) _Float16;
using f32x4 = __attribute__((ext_vector_type(4))) float;
using i32x4 = __attribute__((ext_vector_type(4))) int;

__device__ inline float fast_exp2(float x) {
#if __has_builtin(__builtin_amdgcn_exp2f)
    return __builtin_amdgcn_exp2f(x);
#else
    return exp2f(x);
#endif
}

// h16B frag-ordered layout, per (bh): halves offset =
//   bh*131072 + (j>>5)*2048 + (o>>4)*512 + (((j>>3)&3)*16 + (o&15))*8 + (j&7)
// = 16x16x32 MFMA B-fragment order (n = lane&15, k = 8*(lane>>4)+i).

// ---------------------------------------------------------------------------
// Kernel 1: h = x @ w[h] (fp32), fused tanh -> s_src/s_dst (pre-scaled by
// log2e), h -> fp16 frag order.  512 blocks x 256 threads.
// ---------------------------------------------------------------------------
__global__ __launch_bounds__(256) void k1_proj(
    const float* __restrict__ x, const float* __restrict__ w,
    const float* __restrict__ a_src, const float* __restrict__ a_dst,
    _Float16* __restrict__ h16B, float* __restrict__ ssrc, float* __restrict__ sdst)
{
    __shared__ __align__(16) float w_s[FIN * FOUT];
    __shared__ __align__(16) float xs[64 * 132];

    const int t    = threadIdx.x;
    const int bx   = blockIdx.x;
    const int bh   = bx >> 5;
    const int tile = bx & 31;
    const int b    = bh >> 2;
    const int h    = bh & 3;
    const int n0   = tile * 64;

    {
        const f32x4* wg = (const f32x4*)(w + h * FIN * FOUT);
        f32x4* wl = (f32x4*)w_s;
#pragma unroll
        for (int k = 0; k < 8; ++k) wl[t + 256 * k] = wg[t + 256 * k];
    }
    {
#pragma unroll
        for (int k = 0; k < 8; ++k) {
            int q  = t + 256 * k;
            int r  = q >> 5;
            int c4 = q & 31;
            f32x4 v = *(const f32x4*)(x + (size_t)(b * NN + n0 + r) * FIN + c4 * 4);
            *(f32x4*)(xs + r * 132 + c4 * 4) = v;
        }
    }
    __syncthreads();

    const int ty = t >> 4, tx = t & 15;
    float acc[4][4] = {};

#pragma unroll 4
    for (int f4 = 0; f4 < 32; ++f4) {
        f32x4 xv[4], wv[4];
#pragma unroll
        for (int q = 0; q < 4; ++q)
            xv[q] = *(const f32x4*)(xs + (ty * 4 + q) * 132 + f4 * 4);
#pragma unroll
        for (int k = 0; k < 4; ++k)
            wv[k] = *(const f32x4*)(w_s + (f4 * 4 + k) * 64 + tx * 4);
#pragma unroll
        for (int q = 0; q < 4; ++q)
#pragma unroll
            for (int k = 0; k < 4; ++k)
#pragma unroll
                for (int c = 0; c < 4; ++c)
                    acc[q][c] += xv[q][k] * wv[k][c];
    }

    const int j0 = n0 + ty * 4;
#pragma unroll
    for (int cc = 0; cc < 4; ++cc) {
        int o = tx * 4 + cc;
        f16x4 hv;
#pragma unroll
        for (int q = 0; q < 4; ++q) hv[q] = (_Float16)acc[q][cc];
        int off = bh * 131072 + (j0 >> 5) * 2048 + (o >> 4) * 512
                + (((j0 >> 3) & 3) * 16 + (o & 15)) * 8 + (j0 & 7);
        *(f16x4*)(h16B + off) = hv;
    }

    f32x4 a_s = *(const f32x4*)(a_src + h * FOUT + tx * 4);
    f32x4 a_d = *(const f32x4*)(a_dst + h * FOUT + tx * 4);
    float ss[4], sd[4];
#pragma unroll
    for (int q = 0; q < 4; ++q) {
        float s1 = 0.f, s2 = 0.f;
#pragma unroll
        for (int cc = 0; cc < 4; ++cc) {
            float th = tanhf(acc[q][cc]);
            s1 += th * a_s[cc];
            s2 += th * a_d[cc];
        }
        ss[q] = s1; sd[q] = s2;
    }
#pragma unroll
    for (int m = 1; m <= 8; m <<= 1) {
#pragma unroll
        for (int q = 0; q < 4; ++q) {
            ss[q] += __shfl_xor(ss[q], m);
            sd[q] += __shfl_xor(sd[q], m);
        }
    }
    if (tx == 0) {
#pragma unroll
        for (int q = 0; q < 4; ++q) {
            ssrc[bh * NN + j0 + q] = ss[q] * LOG2E;   // pre-scale: exp -> exp2
            sdst[bh * NN + j0 + q] = sd[q] * LOG2E;
        }
    }
}

// ---------------------------------------------------------------------------
// Kernel 2: barrier-free masked-softmax attention + PV (fp16 MFMA).
// 2048 blocks (16 bh x 128 row-tiles of 16), 256 threads = 4 waves.
// All 4 waves compute the SAME 16 rows; wave wv takes j-chunks with
// index ci % 4 == wv (16 chunks of 32 j each). Register double-buffered
// adj + B; no main-loop barriers. End: 2-round LDS tree combine.
// VGPR budget 64 -> 8 blocks/CU = 32 waves/CU.
// ---------------------------------------------------------------------------
__global__ __launch_bounds__(256, 8) void k2_attn(
    const int* __restrict__ adj,
    const _Float16* __restrict__ h16B,
    const float* __restrict__ ssrc, const float* __restrict__ sdst,
    const float* __restrict__ bias, float* __restrict__ out)
{
    __shared__ __align__(16) float sd_lds[NN];      // 8 KB
    __shared__ __align__(16) float comb[2][64][21]; // 10.75 KB (pad 21: no bank conflict)
    __shared__ float redmax[4];

    const int t    = threadIdx.x;
    const int wv   = t >> 6;          // = j-parity (0..3)
    const int lane = t & 63;
    const int bh   = blockIdx.x >> 7;
    const int i0   = (blockIdx.x & 127) << 4;   // 16-row tile
    const int b    = bh >> 2;
    const int m    = lane & 15;
    const int g    = lane >> 4;

    // ---- stage sdst (scaled) into LDS + block max D ----
    {
        const float* sdp = sdst + bh * NN;
        float dm = -1e30f;
#pragma unroll
        for (int k = 0; k < 8; ++k) {
            float v = sdp[t + 256 * k];
            sd_lds[t + 256 * k] = v;
            dm = fmaxf(dm, v);
        }
#pragma unroll
        for (int msk = 1; msk <= 32; msk <<= 1) dm = fmaxf(dm, __shfl_xor(dm, msk));
        if (lane == 0) redmax[wv] = dm;
    }
    __syncthreads();
    const float D = fmaxf(fmaxf(redmax[0], redmax[1]), fmaxf(redmax[2], redmax[3]));

    const int row = i0 + m;
    const float sA = ssrc[bh * NN + row];
    float c = sA + D; c = fmaxf(c, 0.2f * c);    // leaky(sA+D) >= row max logit
    const float sAc  = sA - c;
    const float sAc2 = fmaf(0.2f, sA, -c);

    const int* adjrow = adj + ((size_t)b * NN + row) * NN + 8 * g;
    const _Float16* Bsrc = h16B + bh * 131072 + lane * 8;

    f32x4 acc0 = {0,0,0,0}, acc1 = {0,0,0,0}, acc2 = {0,0,0,0}, acc3 = {0,0,0,0};
    f32x4 accz = {0,0,0,0};
    f16x8 ones;
#pragma unroll
    for (int i = 0; i < 8; ++i) ones[i] = (_Float16)1.0f;

    // register double buffers (statically named -> no scratch)
    i32x4 avA0, avA1, avB0, avB1;
    f16x8 bA0, bA1, bA2, bA3, bB0, bB1, bB2, bB3;

    // chunk index for slot it (0..15): ci = it*4 + wv
#define LOADP(av0_, av1_, b0_, b1_, b2_, b3_, it_) do {                       \
        const int ci_ = (it_) * 4 + wv;                                       \
        av0_ = *(const i32x4*)(adjrow + ci_ * 32);                            \
        av1_ = *(const i32x4*)(adjrow + ci_ * 32 + 4);                        \
        const _Float16* bb_ = Bsrc + ci_ * 2048;                              \
        b0_ = *(const f16x8*)(bb_);                                           \
        b1_ = *(const f16x8*)(bb_ + 512);                                     \
        b2_ = *(const f16x8*)(bb_ + 1024);                                    \
        b3_ = *(const f16x8*)(bb_ + 1536);                                    \
    } while (0)

#define COMPUTE(av0_, av1_, b0_, b1_, b2_, b3_, it_) do {                     \
        const int ci_ = (it_) * 4 + wv;                                       \
        const float* djp_ = sd_lds + ci_ * 32 + 8 * g;                        \
        f32x4 dj0_ = *(const f32x4*)(djp_);                                   \
        f32x4 dj1_ = *(const f32x4*)(djp_ + 4);                               \
        float ev_[8];                                                         \
        _Pragma("unroll")                                                     \
        for (int i = 0; i < 8; ++i) {                                         \
            float dj = (i < 4) ? dj0_[i] : dj1_[i - 4];                       \
            int   av = (i < 4) ? av0_[i] : av1_[i - 4];                       \
            float a1 = sAc + dj;                                              \
            float a2 = fmaf(0.2f, dj, sAc2);                                  \
            float ee = fast_exp2(fmaxf(a1, a2));                              \
            ev_[i] = av ? ee : 0.0f;                                          \
        }                                                                     \
        union { f16x8 v; f16x2 p[4]; } af_;                                   \
        _Pragma("unroll")                                                     \
        for (int i = 0; i < 4; ++i)                                           \
            af_.p[i] = __builtin_bit_cast(f16x2,                              \
                __builtin_amdgcn_cvt_pkrtz(ev_[2 * i], ev_[2 * i + 1]));      \
        acc0 = __builtin_amdgcn_mfma_f32_16x16x32_f16(af_.v, b0_, acc0, 0, 0, 0); \
        acc1 = __builtin_amdgcn_mfma_f32_16x16x32_f16(af_.v, b1_, acc1, 0, 0, 0); \
        acc2 = __builtin_amdgcn_mfma_f32_16x16x32_f16(af_.v, b2_, acc2, 0, 0, 0); \
        acc3 = __builtin_amdgcn_mfma_f32_16x16x32_f16(af_.v, b3_, acc3, 0, 0, 0); \
        accz = __builtin_amdgcn_mfma_f32_16x16x32_f16(af_.v, ones, accz, 0, 0, 0); \
    } while (0)

    LOADP(avA0, avA1, bA0, bA1, bA2, bA3, 0);
    LOADP(avB0, avB1, bB0, bB1, bB2, bB3, 1);

    for (int ii = 0; ii < 7; ++ii) {
        const int it0 = 2 * ii;
        COMPUTE(avA0, avA1, bA0, bA1, bA2, bA3, it0);
        LOADP(avA0, avA1, bA0, bA1, bA2, bA3, it0 + 2);
        COMPUTE(avB0, avB1, bB0, bB1, bB2, bB3, it0 + 1);
        LOADP(avB0, avB1, bB0, bB1, bB2, bB3, it0 + 3);
    }
    COMPUTE(avA0, avA1, bA0, bA1, bA2, bA3, 14);
    COMPUTE(avB0, avB1, bB0, bB1, bB2, bB3, 15);

#undef LOADP
#undef COMPUTE

    // ---- 2-round tree combine of 4 parity partials ----
    __syncthreads();
    if (wv >= 2) {                       // waves 2,3 publish
        float* cp = &comb[wv - 2][lane][0];
#pragma unroll
        for (int r = 0; r < 4; ++r) {
            cp[0 + r]  = acc0[r];
            cp[4 + r]  = acc1[r];
            cp[8 + r]  = acc2[r];
            cp[12 + r] = acc3[r];
            cp[16 + r] = accz[r];
        }
    }
    __syncthreads();
    if (wv < 2) {                        // waves 0,1 absorb
        const float* cp = &comb[wv][lane][0];
#pragma unroll
        for (int r = 0; r < 4; ++r) {
            acc0[r] += cp[0 + r];
            acc1[r] += cp[4 + r];
            acc2[r] += cp[8 + r];
            acc3[r] += cp[12 + r];
            accz[r] += cp[16 + r];
        }
    }
    __syncthreads();
    if (wv == 1) {                       // wave 1 publishes its sum
        float* cp = &comb[0][lane][0];
#pragma unroll
        for (int r = 0; r < 4; ++r) {
            cp[0 + r]  = acc0[r];
            cp[4 + r]  = acc1[r];
            cp[8 + r]  = acc2[r];
            cp[12 + r] = acc3[r];
            cp[16 + r] = accz[r];
        }
    }
    __syncthreads();
    if (wv == 0) {                       // wave 0 finishes
        const float* cp = &comb[0][lane][0];
        float zs[4];
#pragma unroll
        for (int r = 0; r < 4; ++r) zs[r] = accz[r] + cp[16 + r];
        size_t obase = ((size_t)bh * NN + i0) * FOUT;
        // C/D layout: col = lane&15 (=m), row = g*4 + r
#pragma unroll
        for (int ot = 0; ot < 4; ++ot) {
            float bv = bias[ot * 16 + m];
            f32x4 a = (ot == 0) ? acc0 : (ot == 1) ? acc1 : (ot == 2) ? acc2 : acc3;
#pragma unroll
            for (int r = 0; r < 4; ++r) {
                float v = (a[r] + cp[ot * 4 + r]) / zs[r] + bv;
                out[obase + (size_t)(g * 4 + r) * FOUT + ot * 16 + m] = v;
            }
        }
    }
}

// ---------------------------------------------------------------------------
extern "C" void kernel_launch(void* const* d_in, const int* in_sizes, int n_in,
                              void* d_out, int out_size, void* d_ws, size_t ws_size,
                              hipStream_t stream) {
    (void)in_sizes; (void)n_in; (void)out_size; (void)ws_size;
    const float* x     = (const float*)d_in[0];
    const int*   adj   = (const int*)d_in[1];     // bool -> int32
    const float* w     = (const float*)d_in[2];
    const float* a_src = (const float*)d_in[3];
    const float* a_dst = (const float*)d_in[4];
    const float* bias  = (const float*)d_in[5];
    float*       out   = (float*)d_out;

    _Float16* h16B = (_Float16*)d_ws;                              // 4 MB
    float*    ssrc = (float*)((char*)d_ws + 4194304);              // 128 KB
    float*    sdst = (float*)((char*)d_ws + 4194304 + 131072);     // 128 KB

    k1_proj<<<512, 256, 0, stream>>>(x, w, a_src, a_dst, h16B, ssrc, sdst);
    k2_attn<<<2048, 256, 0, stream>>>(adj, h16B, ssrc, sdst, bias, out);
}

// Round 7
// 55.289 us; speedup vs baseline: 1.2299x; 1.2299x over previous
//
#include <hip/hip_runtime.h>
#include <hip/hip_fp16.h>

#define NN   2048
#define FIN  128
#define FOUT 64
#define LOG2E 1.44269504088896f

using f16x8 = __attribute__((ext_vector_type(8))) _Float16;
using f16x4 = __attribute__((ext_vector_type(4))) _Float16;
using f16x2 = __attribute__((ext_vector_type(2))) _Float16;
using f32x4 = __attribute__((ext_vector_type(4))) float;
using i32x4 = __attribute__((ext_vector_type(4))) int;

__device__ inline float fast_exp2(float x) {
#if __has_builtin(__builtin_amdgcn_exp2f)
    return __builtin_amdgcn_exp2f(x);
#else
    return exp2f(x);
#endif
}

// h16B frag-ordered layout, per (bh): halves offset =
//   bh*131072 + (j>>5)*2048 + (o>>4)*512 + (((j>>3)&3)*16 + (o&15))*8 + (j&7)
// adjbitsT layout: [b][wc(64)][row(2048)] uint32; bit q of word = adj[b][row][wc*32+q]

// ---------------------------------------------------------------------------
// Kernel 1: h = x @ w[h] (fp32) + tanh -> s_src/s_dst (log2e-scaled) + h->fp16
// frag order + adj bitpack (transposed). 512 blocks x 256 threads.
// ---------------------------------------------------------------------------
__global__ __launch_bounds__(256) void k1_proj(
    const float* __restrict__ x, const float* __restrict__ w,
    const float* __restrict__ a_src, const float* __restrict__ a_dst,
    const int* __restrict__ adj,
    _Float16* __restrict__ h16B, float* __restrict__ ssrc, float* __restrict__ sdst,
    unsigned int* __restrict__ adjbitsT)
{
    __shared__ __align__(16) float w_s[FIN * FOUT];
    __shared__ __align__(16) float xs[64 * 132];

    const int t    = threadIdx.x;
    const int bx   = blockIdx.x;
    const int bh   = bx >> 5;
    const int tile = bx & 31;
    const int b    = bh >> 2;
    const int h    = bh & 3;
    const int n0   = tile * 64;

    {
        const f32x4* wg = (const f32x4*)(w + h * FIN * FOUT);
        f32x4* wl = (f32x4*)w_s;
#pragma unroll
        for (int k = 0; k < 8; ++k) wl[t + 256 * k] = wg[t + 256 * k];
    }
    {
#pragma unroll
        for (int k = 0; k < 8; ++k) {
            int q  = t + 256 * k;
            int r  = q >> 5;
            int c4 = q & 31;
            f32x4 v = *(const f32x4*)(x + (size_t)(b * NN + n0 + r) * FIN + c4 * 4);
            *(f32x4*)(xs + r * 132 + c4 * 4) = v;
        }
    }
    __syncthreads();

    const int ty = t >> 4, tx = t & 15;
    float acc[4][4] = {};

#pragma unroll 4
    for (int f4 = 0; f4 < 32; ++f4) {
        f32x4 xv[4], wv[4];
#pragma unroll
        for (int q = 0; q < 4; ++q)
            xv[q] = *(const f32x4*)(xs + (ty * 4 + q) * 132 + f4 * 4);
#pragma unroll
        for (int k = 0; k < 4; ++k)
            wv[k] = *(const f32x4*)(w_s + (f4 * 4 + k) * 64 + tx * 4);
#pragma unroll
        for (int q = 0; q < 4; ++q)
#pragma unroll
            for (int k = 0; k < 4; ++k)
#pragma unroll
                for (int c = 0; c < 4; ++c)
                    acc[q][c] += xv[q][k] * wv[k][c];
    }

    const int j0 = n0 + ty * 4;
#pragma unroll
    for (int cc = 0; cc < 4; ++cc) {
        int o = tx * 4 + cc;
        f16x4 hv;
#pragma unroll
        for (int q = 0; q < 4; ++q) hv[q] = (_Float16)acc[q][cc];
        int off = bh * 131072 + (j0 >> 5) * 2048 + (o >> 4) * 512
                + (((j0 >> 3) & 3) * 16 + (o & 15)) * 8 + (j0 & 7);
        *(f16x4*)(h16B + off) = hv;
    }

    f32x4 a_s = *(const f32x4*)(a_src + h * FOUT + tx * 4);
    f32x4 a_d = *(const f32x4*)(a_dst + h * FOUT + tx * 4);
    float ss[4], sd[4];
#pragma unroll
    for (int q = 0; q < 4; ++q) {
        float s1 = 0.f, s2 = 0.f;
#pragma unroll
        for (int cc = 0; cc < 4; ++cc) {
            float th = tanhf(acc[q][cc]);
            s1 += th * a_s[cc];
            s2 += th * a_d[cc];
        }
        ss[q] = s1; sd[q] = s2;
    }
#pragma unroll
    for (int m = 1; m <= 8; m <<= 1) {
#pragma unroll
        for (int q = 0; q < 4; ++q) {
            ss[q] += __shfl_xor(ss[q], m);
            sd[q] += __shfl_xor(sd[q], m);
        }
    }
    if (tx == 0) {
#pragma unroll
        for (int q = 0; q < 4; ++q) {
            ssrc[bh * NN + j0 + q] = ss[q] * LOG2E;   // pre-scale: exp -> exp2
            sdst[bh * NN + j0 + q] = sd[q] * LOG2E;
        }
    }

    // ---- adj bitpack: block bx packs flat rows [bx*16, bx*16+16) ----
    {
        const int  frow0 = bx * 16;
        const int* asrc  = adj + (size_t)frow0 * NN;
#pragma unroll
        for (int w4 = 0; w4 < 4; ++w4) {
            int widx  = t + 256 * w4;          // 0..1023
            int row_l = widx >> 6;
            int wc    = widx & 63;
            const i32x4* p = (const i32x4*)(asrc + (size_t)row_l * NN + wc * 32);
            unsigned int wbits = 0;
#pragma unroll
            for (int k = 0; k < 8; ++k) {
                i32x4 v = p[k];
                wbits |= (unsigned int)(v[0] & 1) << (4 * k);
                wbits |= (unsigned int)(v[1] & 1) << (4 * k + 1);
                wbits |= (unsigned int)(v[2] & 1) << (4 * k + 2);
                wbits |= (unsigned int)(v[3] & 1) << (4 * k + 3);
            }
            int frow = frow0 + row_l;
            adjbitsT[(size_t)(frow >> 11) * 131072 + (size_t)wc * 2048 + (frow & 2047)] = wbits;
        }
    }
}

// ---------------------------------------------------------------------------
// Kernel 2: masked-softmax attention + PV. 512 blocks (16 bh x 32 tiles of 64
// rows) x 512 threads (8 waves). Wave w = (rg = w>>1 row-group of 16 rows,
// par = w&1 j-subchunk). Per step s (32 steps of 64 j): double-buffered LDS B
// stage (global_load_lds, counted vmcnt(1)) | e-gen from LDS-resident adj
// bits + sdst | 5 MFMAs | m201-style 2 barriers. Traffic: B 256KB/block.
// ---------------------------------------------------------------------------
__global__ __launch_bounds__(512, 4) void k2_attn(
    const unsigned int* __restrict__ adjbitsT,
    const _Float16* __restrict__ h16B,
    const float* __restrict__ ssrc, const float* __restrict__ sdst,
    const float* __restrict__ bias, float* __restrict__ out)
{
    // smem: [0,16K) Bbuf 2x8KB | [16K,32K) adj words | [32K,40K) sd | [40K,+32) redmax
    // epilogue overlays comb (20KB) on [0,20K)
    __shared__ __align__(16) char smem[41024];
    _Float16*     Bf     = (_Float16*)smem;
    unsigned int* adjw   = (unsigned int*)(smem + 16384);
    float*        sd_lds = (float*)(smem + 32768);
    float*        redmax = (float*)(smem + 40960);
    float*        comb   = (float*)smem;           // [rg][lane][20] after loop

    const int t    = threadIdx.x;
    const int wv   = t >> 6;
    const int lane = t & 63;
    const int bh   = blockIdx.x >> 5;
    const int i0   = (blockIdx.x & 31) << 6;    // 64-row tile
    const int b    = bh >> 2;
    const int rg   = wv >> 1;
    const int par  = wv & 1;
    const int m    = lane & 15;
    const int g    = lane >> 4;

    const _Float16*     Bsrc = h16B + bh * 131072;
    const unsigned int* abT  = adjbitsT + (size_t)b * 131072;

    // ---- prologue staging: adj words (16KB), sdst (8KB), B step 0 (8KB) ----
#pragma unroll
    for (int k = 0; k < 8; ++k) {
        int widx = t + 512 * k;                 // wc = widx>>6, row = widx&63
        __builtin_amdgcn_global_load_lds(
            (const __attribute__((address_space(1))) unsigned int*)(abT + (widx >> 6) * 2048 + i0 + (widx & 63)),
            (__attribute__((address_space(3))) unsigned int*)(adjw + widx), 4, 0, 0);
    }
#pragma unroll
    for (int k = 0; k < 4; ++k) {
        int widx = t + 512 * k;
        __builtin_amdgcn_global_load_lds(
            (const __attribute__((address_space(1))) unsigned int*)(sdst + bh * NN + widx),
            (__attribute__((address_space(3))) unsigned int*)(sd_lds + widx), 4, 0, 0);
    }
    __builtin_amdgcn_global_load_lds(
        (const __attribute__((address_space(1))) unsigned int*)(Bsrc + t * 8),
        (__attribute__((address_space(3))) unsigned int*)(Bf + t * 8), 16, 0, 0);
    asm volatile("s_waitcnt vmcnt(0)" ::: "memory");
    __syncthreads();

    // ---- D = max_j sdst ----
    float dm = -1e30f;
#pragma unroll
    for (int k = 0; k < 4; ++k) dm = fmaxf(dm, sd_lds[t + 512 * k]);
#pragma unroll
    for (int msk = 1; msk <= 32; msk <<= 1) dm = fmaxf(dm, __shfl_xor(dm, msk));
    if (lane == 0) redmax[wv] = dm;
    __syncthreads();
    float D = redmax[0];
#pragma unroll
    for (int k = 1; k < 8; ++k) D = fmaxf(D, redmax[k]);

    const int row = i0 + rg * 16 + m;
    const float sA = ssrc[bh * NN + row];
    float c = sA + D; c = fmaxf(c, 0.2f * c);    // leaky(sA+D) >= row max logit
    const float sAc  = sA - c;
    const float sAc2 = fmaf(0.2f, sA, -c);

    f32x4 acc0 = {0,0,0,0}, acc1 = {0,0,0,0}, acc2 = {0,0,0,0}, acc3 = {0,0,0,0};
    f32x4 accz = {0,0,0,0};
    f16x8 ones;
#pragma unroll
    for (int i = 0; i < 8; ++i) ones[i] = (_Float16)1.0f;

    for (int s = 0; s < 32; ++s) {
        if (s < 31) {
            __builtin_amdgcn_global_load_lds(
                (const __attribute__((address_space(1))) unsigned int*)(Bsrc + (s + 1) * 4096 + t * 8),
                (__attribute__((address_space(3))) unsigned int*)(Bf + ((s + 1) & 1) * 4096 + t * 8),
                16, 0, 0);
            asm volatile("s_waitcnt vmcnt(1)" ::: "memory");   // stage(s) done; stage(s+1) flying
        } else {
            asm volatile("s_waitcnt vmcnt(0)" ::: "memory");
        }
        __builtin_amdgcn_s_barrier();
        __builtin_amdgcn_sched_barrier(0);

        const int ci = 2 * s + par;
        // adj bits: word ci for this row (broadcast across g), byte 8g..8g+7
        unsigned int wb = adjw[ci * 64 + rg * 16 + m] >> (8 * g);
        // sdst window
        const float* djp = sd_lds + ci * 32 + 8 * g;
        f32x4 dj0 = *(const f32x4*)(djp);
        f32x4 dj1 = *(const f32x4*)(djp + 4);
        // B fragments
        const _Float16* bb = Bf + (s & 1) * 4096 + par * 2048 + lane * 8;
        f16x8 b0 = *(const f16x8*)(bb);
        f16x8 b1 = *(const f16x8*)(bb + 512);
        f16x8 b2 = *(const f16x8*)(bb + 1024);
        f16x8 b3 = *(const f16x8*)(bb + 1536);

        float ev[8];
#pragma unroll
        for (int i = 0; i < 8; ++i) {
            float dj = (i < 4) ? dj0[i] : dj1[i - 4];
            float a1 = sAc + dj;
            float a2 = fmaf(0.2f, dj, sAc2);
            float ee = fast_exp2(fmaxf(a1, a2));
            ev[i] = (wb & (1u << i)) ? ee : 0.0f;
        }
        union { f16x8 v; f16x2 p[4]; } af;
#pragma unroll
        for (int i = 0; i < 4; ++i)
            af.p[i] = __builtin_bit_cast(f16x2,
                __builtin_amdgcn_cvt_pkrtz(ev[2 * i], ev[2 * i + 1]));

        acc0 = __builtin_amdgcn_mfma_f32_16x16x32_f16(af.v, b0, acc0, 0, 0, 0);
        acc1 = __builtin_amdgcn_mfma_f32_16x16x32_f16(af.v, b1, acc1, 0, 0, 0);
        acc2 = __builtin_amdgcn_mfma_f32_16x16x32_f16(af.v, b2, acc2, 0, 0, 0);
        acc3 = __builtin_amdgcn_mfma_f32_16x16x32_f16(af.v, b3, acc3, 0, 0, 0);
        accz = __builtin_amdgcn_mfma_f32_16x16x32_f16(af.v, ones, accz, 0, 0, 0);

        __builtin_amdgcn_s_barrier();
    }

    // ---- combine parity partials (overlay comb on Bbuf region) ----
    __syncthreads();
    if (par == 1) {
        float* cp = comb + (rg * 64 + lane) * 20;
#pragma unroll
        for (int r = 0; r < 4; ++r) {
            cp[0 + r]  = acc0[r];
            cp[4 + r]  = acc1[r];
            cp[8 + r]  = acc2[r];
            cp[12 + r] = acc3[r];
            cp[16 + r] = accz[r];
        }
    }
    __syncthreads();
    if (par == 0) {
        const float* cp = comb + (rg * 64 + lane) * 20;
        float zs[4];
#pragma unroll
        for (int r = 0; r < 4; ++r) zs[r] = accz[r] + cp[16 + r];
        size_t obase = ((size_t)bh * NN + i0 + rg * 16) * FOUT;
        // C/D layout: col = lane&15 (=o within tile), row = g*4 + r
#pragma unroll
        for (int ot = 0; ot < 4; ++ot) {
            float bv = bias[ot * 16 + m];
            f32x4 a = (ot == 0) ? acc0 : (ot == 1) ? acc1 : (ot == 2) ? acc2 : acc3;
#pragma unroll
            for (int r = 0; r < 4; ++r) {
                float v = (a[r] + cp[ot * 4 + r]) / zs[r] + bv;
                out[obase + (size_t)(g * 4 + r) * FOUT + ot * 16 + m] = v;
            }
        }
    }
}

// ---------------------------------------------------------------------------
extern "C" void kernel_launch(void* const* d_in, const int* in_sizes, int n_in,
                              void* d_out, int out_size, void* d_ws, size_t ws_size,
                              hipStream_t stream) {
    (void)in_sizes; (void)n_in; (void)out_size; (void)ws_size;
    const float* x     = (const float*)d_in[0];
    const int*   adj   = (const int*)d_in[1];     // bool -> int32
    const float* w     = (const float*)d_in[2];
    const float* a_src = (const float*)d_in[3];
    const float* a_dst = (const float*)d_in[4];
    const float* bias  = (const float*)d_in[5];
    float*       out   = (float*)d_out;

    _Float16*     h16B  = (_Float16*)d_ws;                               // 4 MB
    float*        ssrc  = (float*)((char*)d_ws + 4194304);               // 128 KB
    float*        sdst  = (float*)((char*)d_ws + 4194304 + 131072);      // 128 KB
    unsigned int* abT   = (unsigned int*)((char*)d_ws + 4718592);        // 2 MB

    k1_proj<<<512, 256, 0, stream>>>(x, w, a_src, a_dst, adj, h16B, ssrc, sdst, abT);
    k2_attn<<<512, 512, 0, stream>>>(abT, h16B, ssrc, sdst, bias, out);
}